// Round 3
// baseline (414.502 us; speedup 1.0000x reference)
//
#include <hip/hip_runtime.h>

// out[b][ctr][h][w] = sum_c a[b][c][h][w] * b[b][c][h][w - 40 + ctr], ctr 0..40.
// B=8, C=128, H=192, W=256.  Per (b,h) row: banded A^T*Bp via 16x16x32 bf16 MFMA.
//
// V4: continuous-streaming pipeline (V3 post-mortem: VGPR=64 proved the compiler
// re-serialized the 2-buffer prefetch; loads were front-loaded then the memory
// pipe idled during MFMA/epilogue -> 24% HBM, waves parked at barriers).
//  - 512 blocks x 3 rows each: 12-chunk flattened pipeline, 1-chunk register
//    lookahead that crosses row boundaries (next row's loads in flight during
//    this row's MFMA + epilogue).
//  - single prefetch buffer (freed at CONV, reissued immediately) keeps VGPR
//    moderate; sched_barrier(0) after each ISSUE pins the 8-load burst.
//  - epilogue store loop statically unrolled so vmcnt stays counted (no drain).
//  - barriers remain lgkmcnt-only (vmcnt NEVER drained at barriers).

constexpr int Bsz = 8, Cch = 128, Hh = 192, Ww = 256, NC = 41;
constexpr int CHW = Hh * Ww;          // 49152
constexpr int LDB = 40;               // u16 per spatial row (32 c + 8 pad) = 80 B
constexpr int A_BYTES = 256 * LDB * 2;   // 20480
constexpr int OSTRIDE = 260;          // f32 epilogue row stride (1040 B)
constexpr int RPB = 3;                // rows per block (192 % 3 == 0: no b-crossing)
constexpr int NCHUNK = 4 * RPB;       // 12 pipeline steps
// smem = max(20480 + 304*80 = 44800, 41*260*4 = 42640) = 44800 B

using sh4 = __attribute__((ext_vector_type(4))) short;
using sh8 = __attribute__((ext_vector_type(8))) short;
using fx4 = __attribute__((ext_vector_type(4))) float;

__device__ inline unsigned short f2bf(float x) {   // fp32 -> bf16 RNE
    unsigned int u = __float_as_uint(x);
    u += 0x7fffu + ((u >> 16) & 1u);
    return (unsigned short)(u >> 16);
}

__global__ __launch_bounds__(512, 4)
void corr_mfma(const float* __restrict__ A, const float* __restrict__ B,
               float* __restrict__ O) {
    __shared__ __align__(16) unsigned char smem[44800];
    unsigned short* aT   = (unsigned short*)smem;              // [256 w][40 c] bf16
    unsigned short* bT   = (unsigned short*)(smem + A_BYTES);  // [304 u][40 c] bf16
    float*          outp = (float*)smem;                       // [41][260] f32 (epilogue)

    const int tid  = threadIdx.x;
    const int lane = tid & 63, wave = tid >> 6;
    const int row0 = blockIdx.x * RPB;
    const int bb   = row0 / Hh, h0 = row0 - bb * Hh;

    const float* base_a = A + (size_t)bb * Cch * CHW + (size_t)h0 * Ww;
    const float* base_b = B + (size_t)bb * Cch * CHW + (size_t)h0 * Ww;

    // staging cell: thread loads 4 channels x float4 per tensor per chunk
    const int cg = tid & 7;     // channel subgroup (4 channels each)
    const int w4 = tid >> 3;    // float4 column group 0..63
    const int wi = lane & 15, kg = lane >> 4;

    const float* pa0 = base_a + (size_t)(cg * 4) * CHW + w4 * 4;
    const float* pb0 = base_b + (size_t)(cg * 4) * CHW + w4 * 4;

    fx4 acc[2][4];
#pragma unroll
    for (int i = 0; i < 2; ++i)
#pragma unroll
        for (int j = 0; j < 4; ++j) acc[i][j] = (fx4)0.0f;

    float4 rA[4], rB[4];   // SINGLE prefetch buffer: freed at CONV, reissued

    // chunk G: row = G>>2 (offset Ww floats each), c-chunk = (G&3)*32
#define ISSUE(G)                                                              \
    _Pragma("unroll")                                                         \
    for (int i = 0; i < 4; ++i)                                               \
        rA[i] = *(const float4*)(pa0 + (size_t)(((G) >> 2) * Ww) +            \
                                 (size_t)(((G) & 3) * 32 + i) * CHW);         \
    _Pragma("unroll")                                                         \
    for (int i = 0; i < 4; ++i)                                               \
        rB[i] = *(const float4*)(pb0 + (size_t)(((G) >> 2) * Ww) +            \
                                 (size_t)(((G) & 3) * 32 + i) * CHW);

#define CONV_STORE()                                                          \
    {                                                                         \
        const float* fa = (const float*)&rA[0];                               \
        const float* fb = (const float*)&rB[0];                               \
        _Pragma("unroll")                                                     \
        for (int r = 0; r < 4; ++r) {                                         \
            sh4 s;                                                            \
            _Pragma("unroll")                                                 \
            for (int i = 0; i < 4; ++i) s[i] = (short)f2bf(fa[i * 4 + r]);    \
            *(sh4*)(aT + (w4 * 4 + r) * LDB + cg * 4) = s;                    \
        }                                                                     \
        _Pragma("unroll")                                                     \
        for (int r = 0; r < 4; ++r) {                                         \
            sh4 s;                                                            \
            _Pragma("unroll")                                                 \
            for (int i = 0; i < 4; ++i) s[i] = (short)f2bf(fb[i * 4 + r]);    \
            *(sh4*)(bT + (40 + w4 * 4 + r) * LDB + cg * 4) = s;               \
        }                                                                     \
    }

    // wave owns 32 w's: w = wave*32 + i*16 + wi; u-tiles shared across i,j
#define MFMA_STEP()                                                           \
    {                                                                         \
        const int w0 = wave * 32;                                             \
        sh8 afr[2], bfr[5];                                                   \
        _Pragma("unroll")                                                     \
        for (int i = 0; i < 2; ++i)                                           \
            afr[i] = *(const sh8*)(aT + (w0 + i * 16 + wi) * LDB + kg * 8);   \
        _Pragma("unroll")                                                     \
        for (int t = 0; t < 5; ++t)                                           \
            bfr[t] = *(const sh8*)(bT + (w0 + t * 16 + wi) * LDB + kg * 8);   \
        _Pragma("unroll")                                                     \
        for (int i = 0; i < 2; ++i)                                           \
            _Pragma("unroll")                                                 \
            for (int j = 0; j < 4; ++j)                                       \
                acc[i][j] = __builtin_amdgcn_mfma_f32_16x16x32_bf16(          \
                    bfr[i + j], afr[i], acc[i][j], 0, 0, 0);                  \
    }

    // drain own LDS ops, then barrier; vmcnt deliberately untouched
#define DS_BAR()                                           \
    asm volatile("s_waitcnt lgkmcnt(0)" ::: "memory");     \
    __builtin_amdgcn_s_barrier();                          \
    asm volatile("" ::: "memory");

    // zero b left pad rows u=0..39 (clobbered by each epilogue's outp alias)
#define REZERO()                                           \
    if (tid < 320) {                                       \
        int u = tid >> 3, cz = (tid & 7) * 4;              \
        *(sh4*)(bT + u * LDB + cz) = (sh4)0;               \
    }

    ISSUE(0)
    __builtin_amdgcn_sched_barrier(0);
    REZERO()

#pragma unroll
    for (int g = 0; g < NCHUNK; ++g) {
        const int k = g & 3;
        CONV_STORE()                    // vmcnt-waits for chunk g's 8 loads
        if (k == 0 && g > 0) { REZERO() }   // pad was clobbered by epilogue
        if (g + 1 < NCHUNK) { ISSUE(g + 1) }   // next chunk's loads in flight
        __builtin_amdgcn_sched_barrier(0);     // pin the 8-load burst here
        DS_BAR()                        // staging of chunk g visible
        MFMA_STEP()
        DS_BAR()                        // all waves' fragment reads drained
        if (k == 3) {
            const int r = g >> 2;
            // scatter band entries: D row ui = kg*4+rr, col wi; ctr = 16j+ui-wi
#pragma unroll
            for (int i = 0; i < 2; ++i) {
                const int w0 = wave * 32 + i * 16;
#pragma unroll
                for (int j = 0; j < 4; ++j)
#pragma unroll
                    for (int rr = 0; rr < 4; ++rr) {
                        int ctr = 16 * j + (kg * 4 + rr) - wi;
                        if ((unsigned)ctr <= 40u)
                            outp[ctr * OSTRIDE + w0 + wi] = acc[i][j][rr];
                    }
            }
            DS_BAR()                    // scatter visible
            float* obase = O + ((size_t)bb * NC * Hh + (size_t)(h0 + r)) * Ww;
            // statically unrolled so outstanding-store counts stay compile-time
#pragma unroll
            for (int ii = 0; ii < 6; ++ii) {
                int idx = tid + ii * 512;
                if (idx < NC * 64) {
                    int ctr = idx >> 6, q = idx & 63;
                    float4 v = *(const float4*)(outp + ctr * OSTRIDE + q * 4);
                    *(float4*)(obase + (size_t)ctr * CHW + q * 4) = v;
                }
            }
            DS_BAR()                    // outp reads drained; smem reusable
#pragma unroll
            for (int i = 0; i < 2; ++i)
#pragma unroll
                for (int j = 0; j < 4; ++j) acc[i][j] = (fx4)0.0f;
        }
    }
}

extern "C" void kernel_launch(void* const* d_in, const int* in_sizes, int n_in,
                              void* d_out, int out_size, void* d_ws, size_t ws_size,
                              hipStream_t stream) {
    const float* a = (const float*)d_in[0];
    const float* b = (const float*)d_in[1];
    // d_in[2] = max_displacement (40) — hardcoded.
    float* out = (float*)d_out;
    corr_mfma<<<dim3(Bsz * Hh / RPB), dim3(512), 0, stream>>>(a, b, out);
}

// Round 4
// 404.978 us; speedup vs baseline: 1.0235x; 1.0235x over previous
//
#include <hip/hip_runtime.h>

// out[b][ctr][h][w] = sum_c a[b][c][h][w] * b[b][c][h][w - 40 + ctr], ctr 0..40.
// B=8, C=128, H=192, W=256.  Per (b,h) row: banded A^T*Bp via 16x16x32 bf16 MFMA.
//
// V5: global_load_lds streaming front-end (V3/V4 post-mortem: VGPR=64 proved the
// compiler re-serializes register prefetch, AND the old staging pattern issued
// 128-B bursts scattered over 8 pages/wave-instr -> ~1.9 TB/s plateau).
//  - each wave-instr now reads ONE contiguous 1 KB channel-row straight to LDS
//    via __builtin_amdgcn_global_load_lds(width 16): no VGPRs, cannot be
//    re-serialized, max DRAM burst efficiency, 1 page per instruction.
//  - fp32 rows land in a 2x8KB double-buffered staging area (4 ch/tensor/step);
//    a second LDS pass transposes+converts to the bf16 MFMA tiles.
//  - counted vmcnt(1) per step, NEVER drained at barriers; lgkmcnt-only barriers.
//  - MFMA chunk every 8 steps; frag-read/overwrite hazards closed by dataflow
//    (MFMAs consume frags before the wave reaches the next step's barrier).

constexpr int Bsz = 8, Cch = 128, Hh = 192, Ww = 256, NC = 41;
constexpr int CHW = Hh * Ww;            // 49152
constexpr int LDB = 40;                 // u16 per tile row (32 c + 8 pad) = 80 B
constexpr int A_BYTES = 256 * LDB * 2;  // 20480
constexpr int B_BYTES = 304 * LDB * 2;  // 24320
constexpr int STAGE_OFF = A_BYTES + B_BYTES;       // 44800
constexpr int SMEM_BYTES = STAGE_OFF + 2 * 8192;   // 61184 (<= 64 KB)
constexpr int OSTRIDE = 260;            // f32 epilogue row stride (1040 B)

using sh4 = __attribute__((ext_vector_type(4))) short;
using sh8 = __attribute__((ext_vector_type(8))) short;
using fx4 = __attribute__((ext_vector_type(4))) float;

__device__ inline unsigned short f2bf(float x) {   // fp32 -> bf16 RNE
    unsigned int u = __float_as_uint(x);
    u += 0x7fffu + ((u >> 16) & 1u);
    return (unsigned short)(u >> 16);
}

typedef const __attribute__((address_space(1))) void gv_t;
typedef __attribute__((address_space(3))) void lv_t;
#define GLL(g, l) __builtin_amdgcn_global_load_lds((gv_t*)(g), (lv_t*)(l), 16, 0, 0)
#define VMWAIT(N) asm volatile("s_waitcnt vmcnt(" #N ")" ::: "memory")
#define LGKM0()   asm volatile("s_waitcnt lgkmcnt(0)" ::: "memory")
#define BAR()     __builtin_amdgcn_s_barrier()

__global__ __launch_bounds__(512, 4)
void corr_mfma(const float* __restrict__ A, const float* __restrict__ B,
               float* __restrict__ O) {
    __shared__ __align__(16) unsigned char smem[SMEM_BYTES];
    unsigned short* aT   = (unsigned short*)smem;              // [256 w][40 c] bf16
    unsigned short* bT   = (unsigned short*)(smem + A_BYTES);  // [304 u][40 c] bf16
    float*          stg  = (float*)(smem + STAGE_OFF);         // [2][8][256] f32
    float*          outp = (float*)smem;                       // [41][260] f32 alias

    const int tid  = threadIdx.x;
    const int lane = tid & 63, wave = tid >> 6;
    const int row  = blockIdx.x;
    const int bb   = row / Hh, h = row - bb * Hh;

    // stage role: waves 0-3 load a-channels, waves 4-7 load b-channels.
    // step s loads channel c = s*4 + (wave&3): one contiguous 1 KB row / wave.
    const float* gsrc0 = ((wave < 4) ? A : B)
                       + (size_t)bb * Cch * CHW + (size_t)h * Ww
                       + (size_t)(wave & 3) * CHW + lane * 4;
    // LDS dest is wave-uniform; HW scatters lane i at +16*i (linear row).
    float* ldst0 = stg + wave * 256;

    // convert role: tt=0 (waves 0-3) -> aT, tt=1 (waves 4-7) -> bT (+40 shift)
    const int tt = tid >> 8, wcol = tid & 255;
    const float* cstg = stg + tt * 1024 + wcol;                 // + buf*2048 + ci*256
    unsigned short* tdst = tt ? (bT + (40 + wcol) * LDB) : (aT + wcol * LDB);

    const int wi = lane & 15, kg = lane >> 4;

    fx4 acc[2][4];
#pragma unroll
    for (int i = 0; i < 2; ++i)
#pragma unroll
        for (int j = 0; j < 4; ++j) acc[i][j] = (fx4)0.0f;

#define GISSUE(S) GLL(gsrc0 + (size_t)(S) * 4 * CHW, ldst0 + ((S) & 1) * 2048)

#define CONVERT(S)                                                            \
    {                                                                         \
        const float* sp = cstg + ((S) & 1) * 2048;                            \
        float f0 = sp[0], f1 = sp[256], f2 = sp[512], f3 = sp[768];           \
        sh4 v;                                                                \
        v[0] = (short)f2bf(f0); v[1] = (short)f2bf(f1);                       \
        v[2] = (short)f2bf(f2); v[3] = (short)f2bf(f3);                       \
        *(sh4*)(tdst + ((S) & 7) * 4) = v;                                    \
    }

#define MFMA_STEP()                                                           \
    {                                                                         \
        const int w0 = wave * 32;                                             \
        sh8 afr[2], bfr[5];                                                   \
        _Pragma("unroll")                                                     \
        for (int i = 0; i < 2; ++i)                                           \
            afr[i] = *(const sh8*)(aT + (w0 + i * 16 + wi) * LDB + kg * 8);   \
        _Pragma("unroll")                                                     \
        for (int t = 0; t < 5; ++t)                                           \
            bfr[t] = *(const sh8*)(bT + (w0 + t * 16 + wi) * LDB + kg * 8);   \
        _Pragma("unroll")                                                     \
        for (int i = 0; i < 2; ++i)                                           \
            _Pragma("unroll")                                                 \
            for (int j = 0; j < 4; ++j)                                       \
                acc[i][j] = __builtin_amdgcn_mfma_f32_16x16x32_bf16(          \
                    bfr[i + j], afr[i], acc[i][j], 0, 0, 0);                  \
    }

    GISSUE(0);
    GISSUE(1);
    // zero bT pad rows once: u=0..39 (left pad) and u=296..303 (right edge,
    // read by wave 7's frags but always discarded; zero to avoid junk).
    if (tid < 320) {
        int u = tid >> 3, cz = (tid & 7) * 4;
        *(sh4*)(bT + u * LDB + cz) = (sh4)0;
    } else if (tid < 384) {
        int x = tid - 320;
        int u = 296 + (x >> 3), cz = (x & 7) * 4;
        *(sh4*)(bT + u * LDB + cz) = (sh4)0;
    }

#pragma unroll
    for (int k = 0; k < 4; ++k) {
#pragma unroll
        for (int j = 0; j < 8; ++j) {
            const int s = k * 8 + j;
            if (s < 31) { VMWAIT(1); } else { VMWAIT(0); }
            BAR();                     // everyone's step-s rows are in staging
            CONVERT(s)
            LGKM0();                   // own staging reads (and tile write) done
            BAR();                     // all waves done reading buf[s&1]
            if (s + 2 < 32) { GISSUE(s + 2); }   // refill freed buffer
        }
        MFMA_STEP()                    // tile for chunk k complete (lgkm+bar'd)
        // no barrier needed after: each wave's MFMAs consume its frag reads
        // before the wave can reach the next step's barrier (dataflow waits).
    }

    LGKM0();
    BAR();                             // smem now reusable as outp
    // scatter band entries: D row ui = kg*4+rr, col wi; ctr = 16j + ui - wi
#pragma unroll
    for (int i = 0; i < 2; ++i) {
        const int w0 = wave * 32 + i * 16;
#pragma unroll
        for (int j = 0; j < 4; ++j)
#pragma unroll
            for (int rr = 0; rr < 4; ++rr) {
                int ctr = 16 * j + (kg * 4 + rr) - wi;
                if ((unsigned)ctr <= 40u) outp[ctr * OSTRIDE + w0 + wi] = acc[i][j][rr];
            }
    }
    LGKM0();
    BAR();
    // coalesced float4 store of the [41][256] plane
    float* obase = O + ((size_t)bb * NC * Hh + (size_t)h) * Ww;
#pragma unroll
    for (int ii = 0; ii < 6; ++ii) {
        int idx = tid + ii * 512;
        if (idx < NC * 64) {
            int ctr = idx >> 6, q = idx & 63;
            float4 v = *(const float4*)(outp + ctr * OSTRIDE + q * 4);
            *(float4*)(obase + (size_t)ctr * CHW + q * 4) = v;
        }
    }
}

extern "C" void kernel_launch(void* const* d_in, const int* in_sizes, int n_in,
                              void* d_out, int out_size, void* d_ws, size_t ws_size,
                              hipStream_t stream) {
    const float* a = (const float*)d_in[0];
    const float* b = (const float*)d_in[1];
    // d_in[2] = max_displacement (40) — hardcoded.
    float* out = (float*)d_out;
    corr_mfma<<<dim3(Bsz * Hh), dim3(512), 0, stream>>>(a, b, out);
}